// Round 3
// baseline (279.528 us; speedup 1.0000x reference)
//
#include <hip/hip_runtime.h>

// IGANN: per-feature 2-layer MLPs (1->16->16->1), summed over 256 features + linear term.
// f16-input MFMA (fp32 accum) for the per-feature 16x16 fc2 GEMM.
// R3: FCHUNK 32->16 (grid 2048, 8 blocks/CU for occupancy), b2 folded into MFMA C,
//     pkrtz-based f32->f16 packing. launch_bounds(256,8) caps VGPR at 64.

typedef float    f32x4 __attribute__((ext_vector_type(4)));
typedef _Float16 f16x4 __attribute__((ext_vector_type(4)));
typedef _Float16 f16x8 __attribute__((ext_vector_type(8)));
typedef __fp16   pk16x2 __attribute__((ext_vector_type(2)));

#if __has_builtin(__builtin_amdgcn_mfma_f32_16x16x16f16)
#define USE_K16 1
#define MFMA16F16 __builtin_amdgcn_mfma_f32_16x16x16f16
#elif __has_builtin(__builtin_amdgcn_mfma_f32_16x16x16_f16)
#define USE_K16 1
#define MFMA16F16 __builtin_amdgcn_mfma_f32_16x16x16_f16
#else
#define USE_K16 0
#endif

__device__ __forceinline__ f16x4 cvt4(f32x4 v) {
    pk16x2 lo = __builtin_amdgcn_cvt_pkrtz(v[0], v[1]);
    pk16x2 hi = __builtin_amdgcn_cvt_pkrtz(v[2], v[3]);
    union { unsigned u[2]; f16x4 h; } un;
    un.u[0] = __builtin_bit_cast(unsigned, lo);
    un.u[1] = __builtin_bit_cast(unsigned, hi);
    return un.h;
}

#define FCHUNK 16   // features per block (16 groups of 16 = 256)

__global__ __launch_bounds__(256, 8) void igann_kernel(
    const float* __restrict__ x,  const float* __restrict__ la,
    const float* __restrict__ bb, const float* __restrict__ W1,
    const float* __restrict__ b1, const float* __restrict__ W2,
    const float* __restrict__ b2, const float* __restrict__ W3,
    const float* __restrict__ b3, float* __restrict__ out)
{
    const int tid = threadIdx.x;
    const int l   = tid & 63;     // lane
    const int w   = tid >> 6;     // wave in block (0..3)
    const int r   = l & 15;       // MFMA row m (A) / col n (D)
    const int g   = l >> 4;       // k-group
    const int g4  = g * 4;
    const int r16 = r * 16;

    const int rb = blockIdx.x >> 4;    // row block (0..127), 256 rows each
    const int fg = blockIdx.x & 15;    // feature group (0..15)
    const int f0 = fg * FCHUNK;
    const int b0 = rb * 256 + w * 64;  // this wave's first row (64 rows = 4 MFMA tiles)

    const float* xr0 = x + (size_t)(b0 + r) * 256 + f0;

    f32x4 acc[4];     // [tile][j]: D-layout row g4+j, col r
    float lin[4];
    #pragma unroll
    for (int t = 0; t < 4; ++t) { acc[t] = (f32x4){0.f,0.f,0.f,0.f}; lin[t] = 0.f; }
    float b3s = 0.f;

    for (int fi = 0; fi < FCHUNK; fi += 4) {
        f32x4 xv[4];
        #pragma unroll
        for (int t = 0; t < 4; ++t)
            xv[t] = *(const f32x4*)(xr0 + t * 16 * 256 + fi);

        #pragma unroll
        for (int u = 0; u < 4; ++u) {
            const int f = f0 + fi + u;
#if USE_K16
            // A: h1[m=r][k=g4+j]; B: W2[f][n=r][k=g4+j]
            f32x4 w1  = *(const f32x4*)(W1 + f * 16 + g4);
            f32x4 bb1 = *(const f32x4*)(b1 + f * 16 + g4);
            f32x4 w2  = *(const f32x4*)(W2 + (size_t)f * 256 + r16 + g4);
            f16x4 bfrag = cvt4(w2);
#else
            const int kb = (g & 1) * 8;
            f32x4 w1  = *(const f32x4*)(W1 + f * 16 + kb);
            f32x4 w1h = *(const f32x4*)(W1 + f * 16 + kb + 4);
            f32x4 bb1 = *(const f32x4*)(b1 + f * 16 + kb);
            f32x4 bb1h= *(const f32x4*)(b1 + f * 16 + kb + 4);
            f32x4 w2  = *(const f32x4*)(W2 + (size_t)f * 256 + r16 + kb);
            f32x4 w2h = *(const f32x4*)(W2 + (size_t)f * 256 + r16 + kb + 4);
            f16x4 blo = cvt4(w2), bhi = cvt4(w2h);
            f16x8 bfrag;
            #pragma unroll
            for (int j = 0; j < 4; ++j) { bfrag[j] = blo[j]; bfrag[4 + j] = bhi[j]; }
#endif
            const float b2k = b2[f * 16 + r];
            const float w3k = W3[f * 16 + r];
            b3s += b3[f];
            const float av = la[f];
            const f32x4 cinit = {b2k, b2k, b2k, b2k};  // b2 folded into MFMA C

            #pragma unroll
            for (int t = 0; t < 4; ++t) {
                const float xs = xv[t][u];
                lin[t] = fmaf(xs, av, lin[t]);
#if USE_K16
                f32x4 h1;
                #pragma unroll
                for (int j = 0; j < 4; ++j)
                    h1[j] = fmaxf(fmaf(xs, w1[j], bb1[j]), 0.f);
                f16x4 afrag = cvt4(h1);
                f32x4 d = MFMA16F16(afrag, bfrag, cinit, 0, 0, 0);
                #pragma unroll
                for (int j = 0; j < 4; ++j)
                    acc[t][j] += fmaxf(d[j], 0.f) * w3k;
#else
                f32x4 h1a, h1b;
                #pragma unroll
                for (int j = 0; j < 4; ++j) {
                    h1a[j] = fmaxf(fmaf(xs, w1[j],  bb1[j]),  0.f);
                    h1b[j] = fmaxf(fmaf(xs, w1h[j], bb1h[j]), 0.f);
                }
                f16x4 alo = cvt4(h1a), ahi = cvt4(h1b);
                f16x8 afrag;
                #pragma unroll
                for (int j = 0; j < 4; ++j) { afrag[j] = alo[j]; afrag[4 + j] = ahi[j]; }
                f32x4 d = __builtin_amdgcn_mfma_f32_16x16x32_f16(
                    afrag, bfrag, (f32x4){0.f,0.f,0.f,0.f}, 0, 0, 0);
                #pragma unroll
                for (int j = 0; j < 4; ++j)
                    acc[t][j] += fmaxf(fmaf(0.5f, d[j], b2k), 0.f) * w3k;
#endif
            }
        }
    }

    // reduce over the 16 output channels (lanes differing in bits 0..3)
    #pragma unroll
    for (int t = 0; t < 4; ++t)
        #pragma unroll
        for (int j = 0; j < 4; ++j) {
            float v = acc[t][j];
            v += __shfl_xor(v, 1, 64);
            v += __shfl_xor(v, 2, 64);
            v += __shfl_xor(v, 4, 64);
            v += __shfl_xor(v, 8, 64);
            acc[t][j] = v;
        }

    __shared__ float red[4][4][16];   // [wave][tile][row]
    if (r == 0) {
        #pragma unroll
        for (int t = 0; t < 4; ++t)
            #pragma unroll
            for (int j = 0; j < 4; ++j)
                red[w][t][g4 + j] = acc[t][j];
    }
    __syncthreads();

    const float gconst = b3s + (fg == 0 ? bb[0] : 0.f);
    if (l < 16) {
        #pragma unroll
        for (int t = 0; t < 4; ++t) {
            const float v = red[w][t][l] + lin[t] + gconst;
            atomicAdd(out + b0 + t * 16 + l, v);
        }
    }
}

extern "C" void kernel_launch(void* const* d_in, const int* in_sizes, int n_in,
                              void* d_out, int out_size, void* d_ws, size_t ws_size,
                              hipStream_t stream) {
    const float* x  = (const float*)d_in[0];
    const float* la = (const float*)d_in[1];
    const float* bb = (const float*)d_in[2];
    const float* W1 = (const float*)d_in[3];
    const float* b1 = (const float*)d_in[4];
    const float* W2 = (const float*)d_in[5];
    const float* b2 = (const float*)d_in[6];
    const float* W3 = (const float*)d_in[7];
    const float* b3 = (const float*)d_in[8];
    float* out = (float*)d_out;

    (void)hipMemsetAsync(out, 0, (size_t)out_size * sizeof(float), stream);

    dim3 grid(2048), block(256);
    hipLaunchKernelGGL(igann_kernel, grid, block, 0, stream,
                       x, la, bb, W1, b1, W2, b2, W3, b3, out);
}

// Round 4
// 158.584 us; speedup vs baseline: 1.7627x; 1.7627x over previous
//
#include <hip/hip_runtime.h>

// IGANN: per-feature 2-layer MLPs (1->16->16->1), summed over 256 features + linear term.
// f16-input MFMA (fp32 accum) for the per-feature 16x16 fc2 GEMM.
// R4: FCHUNK=16 (grid 2048, ~8 blocks/CU), b2 folded into MFMA C, pkrtz packing.
//     launch_bounds(256,4): VGPR cap 128 — R3's (256,8) forced VGPR=32 and spilled
//     ~850 MB/dispatch to scratch (FETCH 412 MB, WRITE 442 MB). Natural ~68 VGPR fits.

typedef float    f32x4 __attribute__((ext_vector_type(4)));
typedef _Float16 f16x4 __attribute__((ext_vector_type(4)));
typedef _Float16 f16x8 __attribute__((ext_vector_type(8)));
typedef __fp16   pk16x2 __attribute__((ext_vector_type(2)));

#if __has_builtin(__builtin_amdgcn_mfma_f32_16x16x16f16)
#define USE_K16 1
#define MFMA16F16 __builtin_amdgcn_mfma_f32_16x16x16f16
#elif __has_builtin(__builtin_amdgcn_mfma_f32_16x16x16_f16)
#define USE_K16 1
#define MFMA16F16 __builtin_amdgcn_mfma_f32_16x16x16_f16
#else
#define USE_K16 0
#endif

__device__ __forceinline__ f16x4 cvt4(f32x4 v) {
    pk16x2 lo = __builtin_amdgcn_cvt_pkrtz(v[0], v[1]);
    pk16x2 hi = __builtin_amdgcn_cvt_pkrtz(v[2], v[3]);
    union { unsigned u[2]; f16x4 h; } un;
    un.u[0] = __builtin_bit_cast(unsigned, lo);
    un.u[1] = __builtin_bit_cast(unsigned, hi);
    return un.h;
}

#define FCHUNK 16   // features per block (16 groups of 16 = 256)

__global__ __launch_bounds__(256, 4) void igann_kernel(
    const float* __restrict__ x,  const float* __restrict__ la,
    const float* __restrict__ bb, const float* __restrict__ W1,
    const float* __restrict__ b1, const float* __restrict__ W2,
    const float* __restrict__ b2, const float* __restrict__ W3,
    const float* __restrict__ b3, float* __restrict__ out)
{
    const int tid = threadIdx.x;
    const int l   = tid & 63;     // lane
    const int w   = tid >> 6;     // wave in block (0..3)
    const int r   = l & 15;       // MFMA row m (A) / col n (D)
    const int g   = l >> 4;       // k-group
    const int g4  = g * 4;
    const int r16 = r * 16;

    const int rb = blockIdx.x >> 4;    // row block (0..127), 256 rows each
    const int fg = blockIdx.x & 15;    // feature group (0..15)
    const int f0 = fg * FCHUNK;
    const int b0 = rb * 256 + w * 64;  // this wave's first row (64 rows = 4 MFMA tiles)

    const float* xr0 = x + (size_t)(b0 + r) * 256 + f0;

    f32x4 acc[4];     // [tile][j]: D-layout row g4+j, col r
    float lin[4];
    #pragma unroll
    for (int t = 0; t < 4; ++t) { acc[t] = (f32x4){0.f,0.f,0.f,0.f}; lin[t] = 0.f; }
    float b3s = 0.f;

    for (int fi = 0; fi < FCHUNK; fi += 4) {
        f32x4 xv[4];
        #pragma unroll
        for (int t = 0; t < 4; ++t)
            xv[t] = *(const f32x4*)(xr0 + t * 16 * 256 + fi);

        #pragma unroll
        for (int u = 0; u < 4; ++u) {
            const int f = f0 + fi + u;
#if USE_K16
            // A: h1[m=r][k=g4+j]; B: W2[f][n=r][k=g4+j]
            f32x4 w1  = *(const f32x4*)(W1 + f * 16 + g4);
            f32x4 bb1 = *(const f32x4*)(b1 + f * 16 + g4);
            f32x4 w2  = *(const f32x4*)(W2 + (size_t)f * 256 + r16 + g4);
            f16x4 bfrag = cvt4(w2);
#else
            const int kb = (g & 1) * 8;
            f32x4 w1  = *(const f32x4*)(W1 + f * 16 + kb);
            f32x4 w1h = *(const f32x4*)(W1 + f * 16 + kb + 4);
            f32x4 bb1 = *(const f32x4*)(b1 + f * 16 + kb);
            f32x4 bb1h= *(const f32x4*)(b1 + f * 16 + kb + 4);
            f32x4 w2  = *(const f32x4*)(W2 + (size_t)f * 256 + r16 + kb);
            f32x4 w2h = *(const f32x4*)(W2 + (size_t)f * 256 + r16 + kb + 4);
            f16x4 blo = cvt4(w2), bhi = cvt4(w2h);
            f16x8 bfrag;
            #pragma unroll
            for (int j = 0; j < 4; ++j) { bfrag[j] = blo[j]; bfrag[4 + j] = bhi[j]; }
#endif
            const float b2k = b2[f * 16 + r];
            const float w3k = W3[f * 16 + r];
            b3s += b3[f];
            const float av = la[f];
            const f32x4 cinit = {b2k, b2k, b2k, b2k};  // b2 folded into MFMA C

            #pragma unroll
            for (int t = 0; t < 4; ++t) {
                const float xs = xv[t][u];
                lin[t] = fmaf(xs, av, lin[t]);
#if USE_K16
                f32x4 h1;
                #pragma unroll
                for (int j = 0; j < 4; ++j)
                    h1[j] = fmaxf(fmaf(xs, w1[j], bb1[j]), 0.f);
                f16x4 afrag = cvt4(h1);
                f32x4 d = MFMA16F16(afrag, bfrag, cinit, 0, 0, 0);
                #pragma unroll
                for (int j = 0; j < 4; ++j)
                    acc[t][j] += fmaxf(d[j], 0.f) * w3k;
#else
                f32x4 h1a, h1b;
                #pragma unroll
                for (int j = 0; j < 4; ++j) {
                    h1a[j] = fmaxf(fmaf(xs, w1[j],  bb1[j]),  0.f);
                    h1b[j] = fmaxf(fmaf(xs, w1h[j], bb1h[j]), 0.f);
                }
                f16x4 alo = cvt4(h1a), ahi = cvt4(h1b);
                f16x8 afrag;
                #pragma unroll
                for (int j = 0; j < 4; ++j) { afrag[j] = alo[j]; afrag[4 + j] = ahi[j]; }
                f32x4 d = __builtin_amdgcn_mfma_f32_16x16x32_f16(
                    afrag, bfrag, (f32x4){0.f,0.f,0.f,0.f}, 0, 0, 0);
                #pragma unroll
                for (int j = 0; j < 4; ++j)
                    acc[t][j] += fmaxf(fmaf(0.5f, d[j], b2k), 0.f) * w3k;
#endif
            }
        }
    }

    // reduce over the 16 output channels (lanes differing in bits 0..3)
    #pragma unroll
    for (int t = 0; t < 4; ++t)
        #pragma unroll
        for (int j = 0; j < 4; ++j) {
            float v = acc[t][j];
            v += __shfl_xor(v, 1, 64);
            v += __shfl_xor(v, 2, 64);
            v += __shfl_xor(v, 4, 64);
            v += __shfl_xor(v, 8, 64);
            acc[t][j] = v;
        }

    __shared__ float red[4][4][16];   // [wave][tile][row]
    if (r == 0) {
        #pragma unroll
        for (int t = 0; t < 4; ++t)
            #pragma unroll
            for (int j = 0; j < 4; ++j)
                red[w][t][g4 + j] = acc[t][j];
    }
    __syncthreads();

    const float gconst = b3s + (fg == 0 ? bb[0] : 0.f);
    if (l < 16) {
        #pragma unroll
        for (int t = 0; t < 4; ++t) {
            const float v = red[w][t][l] + lin[t] + gconst;
            atomicAdd(out + b0 + t * 16 + l, v);
        }
    }
}

extern "C" void kernel_launch(void* const* d_in, const int* in_sizes, int n_in,
                              void* d_out, int out_size, void* d_ws, size_t ws_size,
                              hipStream_t stream) {
    const float* x  = (const float*)d_in[0];
    const float* la = (const float*)d_in[1];
    const float* bb = (const float*)d_in[2];
    const float* W1 = (const float*)d_in[3];
    const float* b1 = (const float*)d_in[4];
    const float* W2 = (const float*)d_in[5];
    const float* b2 = (const float*)d_in[6];
    const float* W3 = (const float*)d_in[7];
    const float* b3 = (const float*)d_in[8];
    float* out = (float*)d_out;

    (void)hipMemsetAsync(out, 0, (size_t)out_size * sizeof(float), stream);

    dim3 grid(2048), block(256);
    hipLaunchKernelGGL(igann_kernel, grid, block, 0, stream,
                       x, la, bb, W1, b1, W2, b2, W3, b3, out);
}

// Round 6
// 130.097 us; speedup vs baseline: 2.1486x; 1.2190x over previous
//
#include <hip/hip_runtime.h>

// IGANN: per-feature 2-layer MLPs (1->16->16->1), summed over 256 features + linear term.
// f16-input MFMA (fp32 accum) for the per-feature 16x16 fc2 GEMM.
// R6: same as R5 but MFMA called via its real name __builtin_amdgcn_mfma_f32_16x16x16f16
//     (no __has_builtin chain — it breaks on the host pass).
// Structure: x slice staged in LDS (stride-18 pad, <=2-way bank aliasing = free),
//     launch_bounds(256,7) pins VGPR cap 73 just above natural live set (no spill),
//     h1 in packed f16 (v_pk_fma_f16), linear term + b3 sum in per-thread epilogue.

typedef float    f32x4 __attribute__((ext_vector_type(4)));
typedef _Float16 f16x4 __attribute__((ext_vector_type(4)));
typedef __fp16   pk16x2 __attribute__((ext_vector_type(2)));

__device__ __forceinline__ f16x4 cvt4(f32x4 v) {
    pk16x2 lo = __builtin_amdgcn_cvt_pkrtz(v[0], v[1]);
    pk16x2 hi = __builtin_amdgcn_cvt_pkrtz(v[2], v[3]);
    union { unsigned u[2]; f16x4 h; } un;
    un.u[0] = __builtin_bit_cast(unsigned, lo);
    un.u[1] = __builtin_bit_cast(unsigned, hi);
    return un.h;
}

__device__ __forceinline__ f16x4 splat_h(float s) {
    pk16x2 p = __builtin_amdgcn_cvt_pkrtz(s, s);
    unsigned u = __builtin_bit_cast(unsigned, p);
    union { unsigned u[2]; f16x4 h; } un;
    un.u[0] = u; un.u[1] = u;
    return un.h;
}

__device__ __forceinline__ f16x4 relu_h(f16x4 v) {
    f16x4 z = {};
    return __builtin_elementwise_max(v, z);
}

__device__ __forceinline__ f32x4 relu_f(f32x4 v) {
    f32x4 z = {0.f, 0.f, 0.f, 0.f};
    return __builtin_elementwise_max(v, z);
}

#define FCHUNK 16   // features per block (16 groups of 16 = 256)
#define LDSR   18   // padded LDS row stride in floats

__global__ __launch_bounds__(256, 7) void igann_kernel(
    const float* __restrict__ x,  const float* __restrict__ la,
    const float* __restrict__ bb, const float* __restrict__ W1,
    const float* __restrict__ b1, const float* __restrict__ W2,
    const float* __restrict__ b2, const float* __restrict__ W3,
    const float* __restrict__ b3, float* __restrict__ out)
{
    const int tid = threadIdx.x;
    const int l   = tid & 63;     // lane
    const int w   = tid >> 6;     // wave in block (0..3)
    const int r   = l & 15;       // MFMA row m (A) / col n (D)
    const int g   = l >> 4;       // k-group
    const int g4  = g * 4;
    const int r16 = r * 16;

    const int rb = blockIdx.x >> 4;    // row block (0..127), 256 rows each
    const int fg = blockIdx.x & 15;    // feature group (0..15)
    const int f0 = fg * FCHUNK;
    const int rowbase = rb * 256;

    __shared__ float ldsx[256 * LDSR];   // 18 KB: x slice [row][col(16)+pad]
    __shared__ float red[256];           // per-row subnet partial sums

    // ---- stage x slice (coalesced: 4 lanes cover one 64-B row-slice) ----
    {
        const int rr = tid >> 2;          // 0..63
        const int c4 = (tid & 3) * 4;     // 0,4,8,12
        #pragma unroll
        for (int it = 0; it < 4; ++it) {
            const int row = it * 64 + rr;
            f32x4 v = *(const f32x4*)(x + (size_t)(rowbase + row) * 256 + f0 + c4);
            *(f32x4*)(ldsx + row * LDSR + c4) = v;
        }
    }
    __syncthreads();

    const float* xw = ldsx + (w * 64 + r) * LDSR;

    f32x4 acc[4];     // [tile][j]: D row g4+j (batch row within tile), col r (channel)
    #pragma unroll
    for (int t = 0; t < 4; ++t) acc[t] = (f32x4){0.f, 0.f, 0.f, 0.f};

    for (int fi = 0; fi < FCHUNK; fi += 4) {
        f32x4 xv[4];
        #pragma unroll
        for (int t = 0; t < 4; ++t)
            xv[t] = *(const f32x4*)(xw + t * 16 * LDSR + fi);

        #pragma unroll
        for (int u = 0; u < 4; ++u) {
            const int f = f0 + fi + u;
            // A: h1[m=r][k=g4+j]; B: W2[f][n=r][k=g4+j]
            f16x4 w1h = cvt4(*(const f32x4*)(W1 + f * 16 + g4));
            f16x4 b1h = cvt4(*(const f32x4*)(b1 + f * 16 + g4));
            f16x4 bfrag = cvt4(*(const f32x4*)(W2 + (size_t)f * 256 + r16 + g4));
            const float b2k = b2[f * 16 + r];
            const float w3k = W3[f * 16 + r];
            const f32x4 cinit = {b2k, b2k, b2k, b2k};   // b2 folded into MFMA C
            const f32x4 w3k4  = {w3k, w3k, w3k, w3k};

            #pragma unroll
            for (int t = 0; t < 4; ++t) {
                f16x4 xs4 = splat_h(xv[t][u]);
                f16x4 h = relu_h(xs4 * w1h + b1h);      // v_pk_fma_f16 + v_pk_max_f16
                f32x4 d = __builtin_amdgcn_mfma_f32_16x16x16f16(h, bfrag, cinit, 0, 0, 0);
                acc[t] += relu_f(d) * w3k4;
            }
        }
    }

    // reduce over the 16 output channels (lane bits 0..3); r==0 lanes hold row sums
    #pragma unroll
    for (int t = 0; t < 4; ++t)
        #pragma unroll
        for (int j = 0; j < 4; ++j) {
            float v = acc[t][j];
            v += __shfl_xor(v, 1, 64);
            v += __shfl_xor(v, 2, 64);
            v += __shfl_xor(v, 4, 64);
            v += __shfl_xor(v, 8, 64);
            if (r == 0) red[w * 64 + t * 16 + g4 + j] = v;
        }
    __syncthreads();

    // ---- epilogue: thread tid owns local row tid ----
    float lin = 0.f, b3s = 0.f;
    const float* xrow = ldsx + tid * LDSR;
    #pragma unroll
    for (int c = 0; c < 16; ++c) {
        lin = fmaf(xrow[c], la[f0 + c], lin);
        b3s += b3[f0 + c];
    }
    const float v = red[tid] + lin + b3s + (fg == 0 ? bb[0] : 0.f);
    atomicAdd(out + rowbase + tid, v);
}

extern "C" void kernel_launch(void* const* d_in, const int* in_sizes, int n_in,
                              void* d_out, int out_size, void* d_ws, size_t ws_size,
                              hipStream_t stream) {
    const float* x  = (const float*)d_in[0];
    const float* la = (const float*)d_in[1];
    const float* bb = (const float*)d_in[2];
    const float* W1 = (const float*)d_in[3];
    const float* b1 = (const float*)d_in[4];
    const float* W2 = (const float*)d_in[5];
    const float* b2 = (const float*)d_in[6];
    const float* W3 = (const float*)d_in[7];
    const float* b3 = (const float*)d_in[8];
    float* out = (float*)d_out;

    (void)hipMemsetAsync(out, 0, (size_t)out_size * sizeof(float), stream);

    dim3 grid(2048), block(256);
    hipLaunchKernelGGL(igann_kernel, grid, block, 0, stream,
                       x, la, bb, W1, b1, W2, b2, W3, b3, out);
}